// Round 3
// baseline (1742.100 us; speedup 1.0000x reference)
//
#include <hip/hip_runtime.h>
#include <math.h>

// ---------------------------------------------------------------------------
// TransformerEncoder on MI355X (gfx950).
// bf16 MFMA everywhere; h -> q,k -> scores path uses hi/lo bf16-split GEMMs
// (3 MFMA products) because SCALE=sqrt(197) makes softmax near-argmax.
// This round: m97-structure GEMM (global_load_lds width=16, BK=64 for
// single-product GEMMs, linear LDS) + bijective XCD swizzle + split LN.
// (Round-2 resubmission — previous round hit GPUAcquisitionTimeout, no data.)
// ---------------------------------------------------------------------------

#define S_LEN 197
#define DIM   768
#define HDIM  3072
#define BATCH 64
#define NT    (BATCH * S_LEN)   // 12608 tokens
#define NTP   12672             // NT padded to multiple of 128
#define SD    (S_LEN * DIM)     // 151296 elements per batch sample
#define SROWS 208               // scores ws rows per batch (alloc)
#define SCOLS 224               // scores/P cols per batch (K-pad for PV)
#define PROWS 256               // P ws rows per batch (alloc, 2x128 tiles)

typedef __attribute__((ext_vector_type(4))) float  f32x4;
typedef __attribute__((ext_vector_type(8))) short  short8v;
typedef __attribute__((ext_vector_type(4))) short  short4v;
typedef __attribute__((ext_vector_type(4))) unsigned short ushort4v;

__device__ __forceinline__ ushort f2bf(float f) {   // RNE float->bf16 bits
  union { float f; unsigned u; } a; a.f = f;
  unsigned u = a.u;
  u += 0x7FFFu + ((u >> 16) & 1u);
  return (ushort)(u >> 16);
}
__device__ __forceinline__ float b2f(ushort h) {
  union { unsigned u; float f; } a; a.u = ((unsigned)h) << 16;
  return a.f;
}
__device__ __forceinline__ float gelu_f(float x) {  // exact gelu
  return 0.5f * x * (1.0f + erff(x * 0.7071067811865476f));
}
__device__ __forceinline__ void gload16(const void* g, void* l) {
  __builtin_amdgcn_global_load_lds(
      (const __attribute__((address_space(1))) void*)g,
      (__attribute__((address_space(3))) void*)l, 16, 0, 0);
}

// ---------------------------------------------------------------------------
// Weight transpose + bf16 (hi[/lo]) split:  W[K][N] -> T[N][K]
// ---------------------------------------------------------------------------
template<bool SPLIT>
__global__ __launch_bounds__(256) void transp_k(const float* __restrict__ W,
                                                int K, int N,
                                                ushort* __restrict__ Thi,
                                                ushort* __restrict__ Tlo) {
  __shared__ float tile[32][33];
  const int nb = blockIdx.x * 32, kb = blockIdx.y * 32;
  const int tx = threadIdx.x, ty = threadIdx.y;   // (32, 8)
#pragma unroll
  for (int i = 0; i < 4; ++i)
    tile[ty + i * 8][tx] = W[(size_t)(kb + ty + i * 8) * N + nb + tx];
  __syncthreads();
#pragma unroll
  for (int i = 0; i < 4; ++i) {
    float v = tile[tx][ty + i * 8];             // = W[kb+tx][nb+ty+i*8]
    size_t o = (size_t)(nb + ty + i * 8) * K + kb + tx;
    ushort h = f2bf(v);
    Thi[o] = h;
    if (SPLIT) Tlo[o] = f2bf(v - b2f(h));
  }
}

// ---------------------------------------------------------------------------
// LayerNorm, split into partial-reduce / finalize / apply for full-GPU BW
// ---------------------------------------------------------------------------
#define LN_CH 4
__global__ __launch_bounds__(256) void ln_part_k(const float* __restrict__ x,
                                                 float* __restrict__ pbuf) {
  const int c = blockIdx.x, b = blockIdx.y;
  const float4* xv = (const float4*)(x + (size_t)b * SD);
  const int per = (SD / 4) / LN_CH;   // 9456
  float sum = 0.f, sq = 0.f;
  for (int i = c * per + threadIdx.x; i < (c + 1) * per; i += 256) {
    float4 v = xv[i];
    sum += (v.x + v.y) + (v.z + v.w);
    sq  += (v.x * v.x + v.y * v.y) + (v.z * v.z + v.w * v.w);
  }
#pragma unroll
  for (int o = 32; o > 0; o >>= 1) {
    sum += __shfl_xor(sum, o); sq += __shfl_xor(sq, o);
  }
  __shared__ float s1[4], s2[4];
  if ((threadIdx.x & 63) == 0) { s1[threadIdx.x >> 6] = sum; s2[threadIdx.x >> 6] = sq; }
  __syncthreads();
  if (threadIdx.x == 0) {
    pbuf[(b * LN_CH + c) * 2]     = s1[0] + s1[1] + s1[2] + s1[3];
    pbuf[(b * LN_CH + c) * 2 + 1] = s2[0] + s2[1] + s2[2] + s2[3];
  }
}

__global__ __launch_bounds__(64) void ln_fin_k(const float* __restrict__ pbuf,
                                               float* __restrict__ stats) {
  const int b = threadIdx.x;
  float S = 0.f, Q = 0.f;
#pragma unroll
  for (int c = 0; c < LN_CH; ++c) {
    S += pbuf[(b * LN_CH + c) * 2];
    Q += pbuf[(b * LN_CH + c) * 2 + 1];
  }
  const float mu = S / (float)SD;
  const float var = Q / (float)SD - mu * mu;
  stats[b * 2] = mu;
  stats[b * 2 + 1] = 1.0f / sqrtf(var + 1e-5f);
}

template<bool SPLIT>
__global__ __launch_bounds__(256) void ln_apply_k(const float* __restrict__ x,
                                                  const float* __restrict__ w,
                                                  const float* __restrict__ bb,
                                                  const float* __restrict__ stats,
                                                  ushort* __restrict__ oHi,
                                                  ushort* __restrict__ oLo) {
  const int b = blockIdx.y;
  const int i = blockIdx.x * 256 + threadIdx.x;
  if (i >= SD / 4) return;
  const float mu = stats[b * 2], rs = stats[b * 2 + 1];
  float4 v  = ((const float4*)(x + (size_t)b * SD))[i];
  float4 W4 = ((const float4*)w)[i];
  float4 B4 = ((const float4*)bb)[i];
  float h0 = (v.x - mu) * rs * W4.x + B4.x;
  float h1 = (v.y - mu) * rs * W4.y + B4.y;
  float h2 = (v.z - mu) * rs * W4.z + B4.z;
  float h3 = (v.w - mu) * rs * W4.w + B4.w;
  ushort4v hh;
  hh[0] = f2bf(h0); hh[1] = f2bf(h1); hh[2] = f2bf(h2); hh[3] = f2bf(h3);
  ((ushort4v*)(oHi + (size_t)b * SD))[i] = hh;
  if (SPLIT) {
    ushort4v ll;
    ll[0] = f2bf(h0 - b2f(hh[0]));
    ll[1] = f2bf(h1 - b2f(hh[1]));
    ll[2] = f2bf(h2 - b2f(hh[2]));
    ll[3] = f2bf(h3 - b2f(hh[3]));
    ((ushort4v*)(oLo + (size_t)b * SD))[i] = ll;
  }
}

// ---------------------------------------------------------------------------
// Row softmax over 197 valid cols; writes P (bf16) with cols [197,224) zeroed
// ---------------------------------------------------------------------------
__global__ __launch_bounds__(64) void softmax_k(const float* __restrict__ scores,
                                                ushort* __restrict__ P) {
  const int s = blockIdx.x, b = blockIdx.y;
  const int lane = threadIdx.x;
  const float* row = scores + ((size_t)b * SROWS + s) * SCOLS;
  float v[4];
  float m = -1e30f;
#pragma unroll
  for (int t = 0; t < 4; ++t) {
    int c = lane + t * 64;
    v[t] = (c < S_LEN) ? row[c] : -1e30f;
    m = fmaxf(m, v[t]);
  }
#pragma unroll
  for (int off = 32; off > 0; off >>= 1) m = fmaxf(m, __shfl_xor(m, off));
  float sum = 0.f;
#pragma unroll
  for (int t = 0; t < 4; ++t) {
    int c = lane + t * 64;
    v[t] = (c < S_LEN) ? expf(v[t] - m) : 0.f;
    sum += v[t];
  }
#pragma unroll
  for (int off = 32; off > 0; off >>= 1) sum += __shfl_xor(sum, off);
  const float inv = 1.0f / sum;
  ushort* prow = P + ((size_t)b * PROWS + s) * SCOLS;
#pragma unroll
  for (int t = 0; t < 4; ++t) {
    int c = lane + t * 64;
    if (c < SCOLS) prow[c] = f2bf(v[t] * inv);
  }
}

// ---------------------------------------------------------------------------
// MFMA GEMM, m97 structure: C[M][N] = A[M][K] * B^T (B stored [N][K] unless
// TRANSB: B stored [K][N], transposed during LDS staging).
// NPROD==3: hi/lo split (Ahi*Bhi + Ahi*Blo + Alo*Bhi).
// Tile 128x128xBK, 256 threads (4 waves 2x2), mfma_f32_16x16x32_bf16,
// global_load_lds width=16 staging into LINEAR LDS (no padding — required).
// ---------------------------------------------------------------------------
#define GBM 128
#define GBN 128

enum { EPI_QK = 0, EPI_V, EPI_SCORE, EPI_PV, EPI_GELU, EPI_OUT };

struct GemmArgs {
  const ushort* Ahi; const ushort* Alo; size_t sAb; int lda;
  const ushort* Bhi; const ushort* Blo; size_t sBb; int ldb;
  int K; int Mv; int Nv;
  const float* bias;
  const float* resid; size_t sRb; int ldr;
  float scale;
  float* outF; size_t sOb; int ldo;
  ushort* outHi; ushort* outLo;
};

template<int STRIDE>
__device__ __forceinline__ short8v load_frag(const ushort* p) {
  union U { short8v v8; struct P4 { short4v a, b; } p4; } f;
  f.p4.a = *(const short4v*)(p);        // k = 4*g + [0..3]
  f.p4.b = *(const short4v*)(p + 16);   // k = 16 + 4*g + [0..3]
  return f.v8;
}

template<int NPROD, bool TRANSB, int EPI, int BK>
__global__ __launch_bounds__(256) void gemm_k(GemmArgs g) {
  constexpr int KSH  = (BK == 64) ? 6 : 5;
  constexpr int ASZ  = GBM * BK;
  constexpr int BSTR = TRANSB ? 44 : BK;   // 44: 8B-aligned rows, ~8-way wr
  constexpr int BSZ  = GBN * BSTR;
  __shared__ __align__(16) ushort sm[(NPROD == 3) ? (2 * ASZ + 2 * BSZ)
                                                  : (ASZ + BSZ)];
  ushort* sAhi = sm;
  ushort* sBhi = sm + ASZ;
  ushort* sAlo = sm + ASZ + BSZ;       // NPROD==3 only
  ushort* sBlo = sm + 2 * ASZ + BSZ;

  const int tid  = threadIdx.x;
  const int lane = tid & 63;
  const int wid  = tid >> 6;
  const int r    = lane & 15;     // A row / B col / C col
  const int gg   = lane >> 4;     // k-group; C row group
  const int wrow = wid >> 1;
  const int wcol = wid & 1;

  // bijective XCD-aware block swizzle (m204)
  const int gx = gridDim.x, gy = gridDim.y;
  const int nwg = gx * gy;
  const int orig = blockIdx.x + gx * blockIdx.y;
  const int qq = nwg >> 3, rr = nwg & 7;
  const int xcd = orig & 7, idx = orig >> 3;
  const int wg = (xcd < rr ? xcd * (qq + 1) : rr * (qq + 1) + (xcd - rr) * qq) + idx;
  const int nbase = (wg % gx) * GBN;
  const int mbase = (wg / gx) * GBM;
  const int b     = blockIdx.z;

  const ushort* Ahi = g.Ahi + (size_t)b * g.sAb;
  const ushort* Bhi = g.Bhi + (size_t)b * g.sBb;
  const ushort* Alo = (NPROD == 3) ? (g.Alo + (size_t)b * g.sAb) : (const ushort*)nullptr;
  const ushort* Blo = (NPROD == 3) ? (g.Blo + (size_t)b * g.sBb) : (const ushort*)nullptr;

  f32x4 acc[4][4];
#pragma unroll
  for (int i = 0; i < 4; ++i)
#pragma unroll
    for (int j = 0; j < 4; ++j) {
      acc[i][j][0] = 0.f; acc[i][j][1] = 0.f; acc[i][j][2] = 0.f; acc[i][j][3] = 0.f;
    }

  const int wvb = wid << 10;   // wave-uniform LDS byte base within round

  for (int kk = 0; kk < g.K; kk += BK) {
    __syncthreads();
    // ---- stage via global_load_lds (16B/lane, linear LDS) ----
#pragma unroll
    for (int rd = 0; rd < BK / 16; ++rd) {
      const int elem = rd * 2048 + tid * 8;
      const int row = elem >> KSH, col = elem & (BK - 1);
      const size_t gaoff = (size_t)(mbase + row) * g.lda + (kk + col);
      gload16(Ahi + gaoff, (char*)sAhi + rd * 4096 + wvb);
      if (NPROD == 3)
        gload16(Alo + gaoff, (char*)sAlo + rd * 4096 + wvb);
      if (!TRANSB) {
        const size_t gboff = (size_t)(nbase + row) * g.ldb + (kk + col);
        gload16(Bhi + gboff, (char*)sBhi + rd * 4096 + wvb);
        if (NPROD == 3)
          gload16(Blo + gboff, (char*)sBlo + rd * 4096 + wvb);
      }
    }
    if (TRANSB) {
      // B stored [K][N]: read coalesced along N, transpose into LDS [n][k]
#pragma unroll
      for (int rd = 0; rd < (BK * 128) / 2048; ++rd) {
        const int lin = tid * 8 + rd * 2048;
        const int kr = lin >> 7, nc = lin & 127;
        union { short8v v; ushort u[8]; } t;
        t.v = *(const short8v*)(Bhi + (size_t)(kk + kr) * g.ldb + (nbase + nc));
#pragma unroll
        for (int e = 0; e < 8; ++e)
          sBhi[(nc + e) * BSTR + kr] = t.u[e];
      }
    }
    __syncthreads();

    // ---- fragments + MFMA ----
#pragma unroll
    for (int kb = 0; kb < BK / 32; ++kb) {
      short8v aH[4], bH[4], aL[4], bL[4];
#pragma unroll
      for (int i = 0; i < 4; ++i) {
        const int off = (wrow * 64 + i * 16 + r) * BK + kb * 32 + gg * 4;
        aH[i] = load_frag<BK>(sAhi + off);
        if (NPROD == 3) aL[i] = load_frag<BK>(sAlo + off);
      }
#pragma unroll
      for (int j = 0; j < 4; ++j) {
        const int off = (wcol * 64 + j * 16 + r) * BSTR + kb * 32 + gg * 4;
        bH[j] = load_frag<BSTR>(sBhi + off);
        if (NPROD == 3) bL[j] = load_frag<BSTR>(sBlo + off);
      }
#pragma unroll
      for (int i = 0; i < 4; ++i)
#pragma unroll
        for (int j = 0; j < 4; ++j) {
          acc[i][j] = __builtin_amdgcn_mfma_f32_16x16x32_bf16(aH[i], bH[j], acc[i][j], 0, 0, 0);
          if (NPROD == 3) {
            acc[i][j] = __builtin_amdgcn_mfma_f32_16x16x32_bf16(aH[i], bL[j], acc[i][j], 0, 0, 0);
            acc[i][j] = __builtin_amdgcn_mfma_f32_16x16x32_bf16(aL[i], bH[j], acc[i][j], 0, 0, 0);
          }
        }
    }
  }

  // ---- epilogue.  C/D layout: col = lane&15, row = (lane>>4)*4 + reg ----
#pragma unroll
  for (int i = 0; i < 4; ++i)
#pragma unroll
    for (int j = 0; j < 4; ++j)
#pragma unroll
      for (int e = 0; e < 4; ++e) {
        const int row = mbase + wrow * 64 + i * 16 + gg * 4 + e;
        const int col = nbase + wcol * 64 + j * 16 + r;
        float val = acc[i][j][e];
        if (EPI == EPI_QK) {
          val += g.bias[col];
          ushort hi = f2bf(val);
          ushort lo = f2bf(val - b2f(hi));
          size_t o = (size_t)row * g.ldo + col;
          g.outHi[o] = hi; g.outLo[o] = lo;
        } else if (EPI == EPI_V) {
          val += g.bias[col];
          g.outHi[(size_t)row * g.ldo + col] = f2bf(val);
        } else if (EPI == EPI_SCORE) {
          if (row < g.Mv && col < g.Nv)
            (g.outF + (size_t)b * g.sOb)[(size_t)row * g.ldo + col] = val * g.scale;
        } else if (EPI == EPI_PV) {
          if (row < g.Mv) {
            val += (g.resid + (size_t)b * g.sRb)[(size_t)row * g.ldr + col];
            (g.outF + (size_t)b * g.sOb)[(size_t)row * g.ldo + col] = val;
          }
        } else if (EPI == EPI_GELU) {
          val = gelu_f(val + g.bias[col]);
          g.outHi[(size_t)row * g.ldo + col] = f2bf(val);
        } else { // EPI_OUT
          if (row < g.Mv) {
            val = gelu_f(val + g.bias[col]);
            val += g.resid[(size_t)row * g.ldr + col];
            g.outF[(size_t)row * g.ldo + col] = val;
          }
        }
      }
}

// ---------------------------------------------------------------------------
// Host side
// ---------------------------------------------------------------------------
extern "C" void kernel_launch(void* const* d_in, const int* in_sizes, int n_in,
                              void* d_out, int out_size, void* d_ws, size_t ws_size,
                              hipStream_t stream) {
  const float* x   = (const float*)d_in[0];
  const float* n1w = (const float*)d_in[1];
  const float* n1b = (const float*)d_in[2];
  const float* Wq  = (const float*)d_in[3];
  const float* bq  = (const float*)d_in[4];
  const float* Wk  = (const float*)d_in[5];
  const float* bk  = (const float*)d_in[6];
  const float* Wv  = (const float*)d_in[7];
  const float* bv  = (const float*)d_in[8];
  const float* n2w = (const float*)d_in[9];
  const float* n2b = (const float*)d_in[10];
  const float* W1  = (const float*)d_in[11];
  const float* b1  = (const float*)d_in[12];
  const float* W2  = (const float*)d_in[13];
  const float* b2  = (const float*)d_in[14];
  float* out = (float*)d_out;

  char* ws = (char*)d_ws;
  size_t off = 0;
  auto alloc = [&](size_t bytes) -> char* {
    char* p = ws + off;
    off += (bytes + 255) & ~(size_t)255;
    return p;
  };
  const size_t szDD  = (size_t)DIM * DIM * 2;      // 768x768 bf16
  const size_t szDH  = (size_t)DIM * HDIM * 2;     // 768x3072 bf16
  const size_t szAct = (size_t)NTP * DIM * 2;      // padded activation bf16

  ushort* wqtH = (ushort*)alloc(szDD);
  ushort* wqtL = (ushort*)alloc(szDD);
  ushort* wktH = (ushort*)alloc(szDD);
  ushort* wktL = (ushort*)alloc(szDD);
  ushort* wvtH = (ushort*)alloc(szDD);
  ushort* w1tH = (ushort*)alloc(szDH);
  ushort* w2tH = (ushort*)alloc(szDH);
  ushort* hHi  = (ushort*)alloc(szAct);
  ushort* hLo  = (ushort*)alloc(szAct);
  ushort* qHi  = (ushort*)alloc(szAct);
  ushort* qLo  = (ushort*)alloc(szAct);
  ushort* kHi  = (ushort*)alloc(szAct);
  ushort* kLo  = (ushort*)alloc(szAct);
  ushort* vB   = (ushort*)alloc(szAct);
  float*  scoresWs = (float*)alloc((size_t)BATCH * SROWS * SCOLS * 4);
  ushort* pWs      = (ushort*)alloc((size_t)BATCH * PROWS * SCOLS * 2);
  float*  lnPart   = (float*)alloc((size_t)BATCH * LN_CH * 2 * 4);
  float*  lnStats  = (float*)alloc((size_t)BATCH * 2 * 4);
  if (off > ws_size) return;  // workspace too small -> fail loudly

  // Aliases (lifetimes disjoint):
  float*  x2  = (float*)hHi;   // NTP*768*4 == 2 * szAct (hHi+hLo)
  ushort* h2  = vB;            // after PV, v no longer needed
  ushort* hid = qHi;           // NTP*3072*2 == 4 * szAct (qHi..kLo block)

  const float SCALE_F = 14.035668847618199f;  // sqrt(197) == 1/S**(-0.5)

  dim3 tb(32, 8);
  hipLaunchKernelGGL((transp_k<true >), dim3(DIM / 32, DIM / 32), tb, 0, stream, Wq, DIM, DIM, wqtH, wqtL);
  hipLaunchKernelGGL((transp_k<true >), dim3(DIM / 32, DIM / 32), tb, 0, stream, Wk, DIM, DIM, wktH, wktL);
  hipLaunchKernelGGL((transp_k<false>), dim3(DIM / 32, DIM / 32), tb, 0, stream, Wv, DIM, DIM, wvtH, (ushort*)nullptr);
  hipLaunchKernelGGL((transp_k<false>), dim3(HDIM / 32, DIM / 32), tb, 0, stream, W1, DIM, HDIM, w1tH, (ushort*)nullptr);
  hipLaunchKernelGGL((transp_k<false>), dim3(DIM / 32, HDIM / 32), tb, 0, stream, W2, HDIM, DIM, w2tH, (ushort*)nullptr);

  const int APPLY_BX = (SD / 4 + 255) / 256;
  hipLaunchKernelGGL(ln_part_k, dim3(LN_CH, BATCH), dim3(256), 0, stream, x, lnPart);
  hipLaunchKernelGGL(ln_fin_k, dim3(1), dim3(64), 0, stream, lnPart, lnStats);
  hipLaunchKernelGGL((ln_apply_k<true>), dim3(APPLY_BX, BATCH), dim3(256), 0, stream,
                     x, n1w, n1b, lnStats, hHi, hLo);

  GemmArgs a;
  const int BIG = 0x40000000;

  // Q projection (split, BK=32)
  a = GemmArgs{};
  a.Ahi = hHi; a.Alo = hLo; a.sAb = 0; a.lda = DIM;
  a.Bhi = wqtH; a.Blo = wqtL; a.sBb = 0; a.ldb = DIM;
  a.K = DIM; a.Mv = BIG; a.Nv = BIG; a.bias = bq; a.scale = 1.f;
  a.outHi = qHi; a.outLo = qLo; a.ldo = DIM;
  hipLaunchKernelGGL((gemm_k<3, false, EPI_QK, 32>), dim3(DIM / GBN, NTP / GBM, 1), dim3(256), 0, stream, a);
  // K projection (split)
  a.Bhi = wktH; a.Blo = wktL; a.bias = bk; a.outHi = kHi; a.outLo = kLo;
  hipLaunchKernelGGL((gemm_k<3, false, EPI_QK, 32>), dim3(DIM / GBN, NTP / GBM, 1), dim3(256), 0, stream, a);
  // V projection (single, BK=64)
  a = GemmArgs{};
  a.Ahi = hHi; a.sAb = 0; a.lda = DIM;
  a.Bhi = wvtH; a.sBb = 0; a.ldb = DIM;
  a.K = DIM; a.Mv = BIG; a.Nv = BIG; a.bias = bv;
  a.outHi = vB; a.ldo = DIM;
  hipLaunchKernelGGL((gemm_k<1, false, EPI_V, 64>), dim3(DIM / GBN, NTP / GBM, 1), dim3(256), 0, stream, a);

  // scores = SCALE * q k^T  (batched, split)
  a = GemmArgs{};
  a.Ahi = qHi; a.Alo = qLo; a.sAb = (size_t)SD; a.lda = DIM;
  a.Bhi = kHi; a.Blo = kLo; a.sBb = (size_t)SD; a.ldb = DIM;
  a.K = DIM; a.Mv = S_LEN; a.Nv = S_LEN; a.scale = SCALE_F;
  a.outF = scoresWs; a.sOb = (size_t)SROWS * SCOLS; a.ldo = SCOLS;
  hipLaunchKernelGGL((gemm_k<3, false, EPI_SCORE, 32>), dim3(2, 2, BATCH), dim3(256), 0, stream, a);

  hipLaunchKernelGGL(softmax_k, dim3(S_LEN, BATCH), dim3(64), 0, stream, scoresWs, pWs);

  // x2 = P v + x  (batched; B = v stored [K][N] -> TRANSB staging, BK=32)
  a = GemmArgs{};
  a.Ahi = pWs; a.sAb = (size_t)PROWS * SCOLS; a.lda = SCOLS;
  a.Bhi = vB; a.sBb = (size_t)SD; a.ldb = DIM;
  a.K = SCOLS; a.Mv = S_LEN; a.Nv = BIG;
  a.resid = x; a.sRb = (size_t)SD; a.ldr = DIM;
  a.outF = x2; a.sOb = (size_t)SD; a.ldo = DIM;
  hipLaunchKernelGGL((gemm_k<1, true, EPI_PV, 32>), dim3(DIM / GBN, 2, BATCH), dim3(256), 0, stream, a);

  hipLaunchKernelGGL(ln_part_k, dim3(LN_CH, BATCH), dim3(256), 0, stream, x2, lnPart);
  hipLaunchKernelGGL(ln_fin_k, dim3(1), dim3(64), 0, stream, lnPart, lnStats);
  hipLaunchKernelGGL((ln_apply_k<false>), dim3(APPLY_BX, BATCH), dim3(256), 0, stream,
                     x2, n2w, n2b, lnStats, h2, (ushort*)nullptr);

  // hid = gelu(h2 W1 + b1)
  a = GemmArgs{};
  a.Ahi = h2; a.sAb = 0; a.lda = DIM;
  a.Bhi = w1tH; a.sBb = 0; a.ldb = DIM;
  a.K = DIM; a.Mv = BIG; a.Nv = BIG; a.bias = b1;
  a.outHi = hid; a.ldo = HDIM;
  hipLaunchKernelGGL((gemm_k<1, false, EPI_GELU, 64>), dim3(HDIM / GBN, NTP / GBM, 1), dim3(256), 0, stream, a);

  // out = gelu(hid W2 + b2) + x2
  a = GemmArgs{};
  a.Ahi = hid; a.sAb = 0; a.lda = HDIM;
  a.Bhi = w2tH; a.sBb = 0; a.ldb = HDIM;
  a.K = HDIM; a.Mv = NT; a.Nv = BIG; a.bias = b2;
  a.resid = x2; a.sRb = 0; a.ldr = DIM;
  a.outF = out; a.sOb = 0; a.ldo = DIM;
  hipLaunchKernelGGL((gemm_k<1, false, EPI_OUT, 64>), dim3(DIM / GBN, NTP / GBM, 1), dim3(256), 0, stream, a);
}

// Round 4
// 937.220 us; speedup vs baseline: 1.8588x; 1.8588x over previous
//
#include <hip/hip_runtime.h>
#include <math.h>

// ---------------------------------------------------------------------------
// TransformerEncoder on MI355X (gfx950).
// bf16 MFMA everywhere; h -> q,k -> scores path uses hi/lo bf16-split GEMMs
// (3 MFMA products) because SCALE=sqrt(197) makes softmax near-argmax.
// Round 4: fix the 16-way LDS bank conflict introduced by linear LDS +
// global_load_lds: 16B-slot XOR swizzle (T2) applied on BOTH sides —
// pre-swizzled global source (write side is linear per HW) + swizzled
// fragment reads. physical_slot = logical_slot ^ (row & SMASK).
// ---------------------------------------------------------------------------

#define S_LEN 197
#define DIM   768
#define HDIM  3072
#define BATCH 64
#define NT    (BATCH * S_LEN)   // 12608 tokens
#define NTP   12672             // NT padded to multiple of 128
#define SD    (S_LEN * DIM)     // 151296 elements per batch sample
#define SROWS 208               // scores ws rows per batch (alloc)
#define SCOLS 224               // scores/P cols per batch (K-pad for PV)
#define PROWS 256               // P ws rows per batch (alloc, 2x128 tiles)

typedef __attribute__((ext_vector_type(4))) float  f32x4;
typedef __attribute__((ext_vector_type(8))) short  short8v;
typedef __attribute__((ext_vector_type(4))) short  short4v;
typedef __attribute__((ext_vector_type(4))) unsigned short ushort4v;

__device__ __forceinline__ ushort f2bf(float f) {   // RNE float->bf16 bits
  union { float f; unsigned u; } a; a.f = f;
  unsigned u = a.u;
  u += 0x7FFFu + ((u >> 16) & 1u);
  return (ushort)(u >> 16);
}
__device__ __forceinline__ float b2f(ushort h) {
  union { unsigned u; float f; } a; a.u = ((unsigned)h) << 16;
  return a.f;
}
__device__ __forceinline__ float gelu_f(float x) {  // exact gelu
  return 0.5f * x * (1.0f + erff(x * 0.7071067811865476f));
}
__device__ __forceinline__ void gload16(const void* g, void* l) {
  __builtin_amdgcn_global_load_lds(
      (const __attribute__((address_space(1))) void*)g,
      (__attribute__((address_space(3))) void*)l, 16, 0, 0);
}

// ---------------------------------------------------------------------------
// Weight transpose + bf16 (hi[/lo]) split:  W[K][N] -> T[N][K]
// ---------------------------------------------------------------------------
template<bool SPLIT>
__global__ __launch_bounds__(256) void transp_k(const float* __restrict__ W,
                                                int K, int N,
                                                ushort* __restrict__ Thi,
                                                ushort* __restrict__ Tlo) {
  __shared__ float tile[32][33];
  const int nb = blockIdx.x * 32, kb = blockIdx.y * 32;
  const int tx = threadIdx.x, ty = threadIdx.y;   // (32, 8)
#pragma unroll
  for (int i = 0; i < 4; ++i)
    tile[ty + i * 8][tx] = W[(size_t)(kb + ty + i * 8) * N + nb + tx];
  __syncthreads();
#pragma unroll
  for (int i = 0; i < 4; ++i) {
    float v = tile[tx][ty + i * 8];             // = W[kb+tx][nb+ty+i*8]
    size_t o = (size_t)(nb + ty + i * 8) * K + kb + tx;
    ushort h = f2bf(v);
    Thi[o] = h;
    if (SPLIT) Tlo[o] = f2bf(v - b2f(h));
  }
}

// ---------------------------------------------------------------------------
// LayerNorm, split into partial-reduce / finalize / apply for full-GPU BW
// ---------------------------------------------------------------------------
#define LN_CH 4
__global__ __launch_bounds__(256) void ln_part_k(const float* __restrict__ x,
                                                 float* __restrict__ pbuf) {
  const int c = blockIdx.x, b = blockIdx.y;
  const float4* xv = (const float4*)(x + (size_t)b * SD);
  const int per = (SD / 4) / LN_CH;   // 9456
  float sum = 0.f, sq = 0.f;
  for (int i = c * per + threadIdx.x; i < (c + 1) * per; i += 256) {
    float4 v = xv[i];
    sum += (v.x + v.y) + (v.z + v.w);
    sq  += (v.x * v.x + v.y * v.y) + (v.z * v.z + v.w * v.w);
  }
#pragma unroll
  for (int o = 32; o > 0; o >>= 1) {
    sum += __shfl_xor(sum, o); sq += __shfl_xor(sq, o);
  }
  __shared__ float s1[4], s2[4];
  if ((threadIdx.x & 63) == 0) { s1[threadIdx.x >> 6] = sum; s2[threadIdx.x >> 6] = sq; }
  __syncthreads();
  if (threadIdx.x == 0) {
    pbuf[(b * LN_CH + c) * 2]     = s1[0] + s1[1] + s1[2] + s1[3];
    pbuf[(b * LN_CH + c) * 2 + 1] = s2[0] + s2[1] + s2[2] + s2[3];
  }
}

__global__ __launch_bounds__(64) void ln_fin_k(const float* __restrict__ pbuf,
                                               float* __restrict__ stats) {
  const int b = threadIdx.x;
  float S = 0.f, Q = 0.f;
#pragma unroll
  for (int c = 0; c < LN_CH; ++c) {
    S += pbuf[(b * LN_CH + c) * 2];
    Q += pbuf[(b * LN_CH + c) * 2 + 1];
  }
  const float mu = S / (float)SD;
  const float var = Q / (float)SD - mu * mu;
  stats[b * 2] = mu;
  stats[b * 2 + 1] = 1.0f / sqrtf(var + 1e-5f);
}

template<bool SPLIT>
__global__ __launch_bounds__(256) void ln_apply_k(const float* __restrict__ x,
                                                  const float* __restrict__ w,
                                                  const float* __restrict__ bb,
                                                  const float* __restrict__ stats,
                                                  ushort* __restrict__ oHi,
                                                  ushort* __restrict__ oLo) {
  const int b = blockIdx.y;
  const int i = blockIdx.x * 256 + threadIdx.x;
  if (i >= SD / 4) return;
  const float mu = stats[b * 2], rs = stats[b * 2 + 1];
  float4 v  = ((const float4*)(x + (size_t)b * SD))[i];
  float4 W4 = ((const float4*)w)[i];
  float4 B4 = ((const float4*)bb)[i];
  float h0 = (v.x - mu) * rs * W4.x + B4.x;
  float h1 = (v.y - mu) * rs * W4.y + B4.y;
  float h2 = (v.z - mu) * rs * W4.z + B4.z;
  float h3 = (v.w - mu) * rs * W4.w + B4.w;
  ushort4v hh;
  hh[0] = f2bf(h0); hh[1] = f2bf(h1); hh[2] = f2bf(h2); hh[3] = f2bf(h3);
  ((ushort4v*)(oHi + (size_t)b * SD))[i] = hh;
  if (SPLIT) {
    ushort4v ll;
    ll[0] = f2bf(h0 - b2f(hh[0]));
    ll[1] = f2bf(h1 - b2f(hh[1]));
    ll[2] = f2bf(h2 - b2f(hh[2]));
    ll[3] = f2bf(h3 - b2f(hh[3]));
    ((ushort4v*)(oLo + (size_t)b * SD))[i] = ll;
  }
}

// ---------------------------------------------------------------------------
// Row softmax over 197 valid cols; writes P (bf16) with cols [197,224) zeroed
// ---------------------------------------------------------------------------
__global__ __launch_bounds__(64) void softmax_k(const float* __restrict__ scores,
                                                ushort* __restrict__ P) {
  const int s = blockIdx.x, b = blockIdx.y;
  const int lane = threadIdx.x;
  const float* row = scores + ((size_t)b * SROWS + s) * SCOLS;
  float v[4];
  float m = -1e30f;
#pragma unroll
  for (int t = 0; t < 4; ++t) {
    int c = lane + t * 64;
    v[t] = (c < S_LEN) ? row[c] : -1e30f;
    m = fmaxf(m, v[t]);
  }
#pragma unroll
  for (int off = 32; off > 0; off >>= 1) m = fmaxf(m, __shfl_xor(m, off));
  float sum = 0.f;
#pragma unroll
  for (int t = 0; t < 4; ++t) {
    int c = lane + t * 64;
    v[t] = (c < S_LEN) ? expf(v[t] - m) : 0.f;
    sum += v[t];
  }
#pragma unroll
  for (int off = 32; off > 0; off >>= 1) sum += __shfl_xor(sum, off);
  const float inv = 1.0f / sum;
  ushort* prow = P + ((size_t)b * PROWS + s) * SCOLS;
#pragma unroll
  for (int t = 0; t < 4; ++t) {
    int c = lane + t * 64;
    if (c < SCOLS) prow[c] = f2bf(v[t] * inv);
  }
}

// ---------------------------------------------------------------------------
// MFMA GEMM, m97 structure: C[M][N] = A[M][K] * B^T (B stored [N][K] unless
// TRANSB: B stored [K][N], transposed during LDS staging).
// NPROD==3: hi/lo split (Ahi*Bhi + Ahi*Blo + Alo*Bhi).
// Tile 128x128xBK, 256 threads (4 waves 2x2), mfma_f32_16x16x32_bf16,
// global_load_lds width=16 into linear LDS with 16B-slot XOR swizzle:
//   physical_slot = logical_slot ^ (row & SMASK)    (involution)
// write side: pre-swizzle the per-lane GLOBAL source column;
// read side: apply the same XOR to each 8B fragment chunk's 16B slot.
// ---------------------------------------------------------------------------
#define GBM 128
#define GBN 128

enum { EPI_QK = 0, EPI_V, EPI_SCORE, EPI_PV, EPI_GELU, EPI_OUT };

struct GemmArgs {
  const ushort* Ahi; const ushort* Alo; size_t sAb; int lda;
  const ushort* Bhi; const ushort* Blo; size_t sBb; int ldb;
  int K; int Mv; int Nv;
  const float* bias;
  const float* resid; size_t sRb; int ldr;
  float scale;
  float* outF; size_t sOb; int ldo;
  ushort* outHi; ushort* outLo;
};

// swizzled fragment load from a linear [128][BK] bf16 tile.
// cb = byte offset of k-chunk within row (kb*64 + gg*8); reads cb and cb+32.
template<int BK>
__device__ __forceinline__ short8v frag_ld(const ushort* tile, int row, int cb) {
  constexpr int SMASK = (BK * 2) / 16 - 1;      // 7 (BK=64) or 3 (BK=32)
  const char* base = (const char*)tile + row * (BK * 2);
  const int xr = (row & SMASK) << 4;
  const int c1 = cb + 32;
  union U { short8v v8; struct P4 { short4v a, b; } p4; } f;
  f.p4.a = *(const short4v*)(base + ((( cb & ~15) ^ xr) | (cb & 15)));
  f.p4.b = *(const short4v*)(base + (((c1 & ~15) ^ xr) | (c1 & 15)));
  return f.v8;
}

// plain (padded-stride) fragment load — TRANSB register-staged B tile
__device__ __forceinline__ short8v load_frag(const ushort* p) {
  union U { short8v v8; struct P4 { short4v a, b; } p4; } f;
  f.p4.a = *(const short4v*)(p);        // k = 4*g + [0..3]
  f.p4.b = *(const short4v*)(p + 16);   // k = 16 + 4*g + [0..3]
  return f.v8;
}

template<int NPROD, bool TRANSB, int EPI, int BK>
__global__ __launch_bounds__(256) void gemm_k(GemmArgs g) {
  constexpr int KSH2 = (BK == 64) ? 7 : 6;   // log2(bytes per row)
  constexpr int SMASK = (BK * 2) / 16 - 1;
  constexpr int ASZ  = GBM * BK;
  constexpr int BSTR = TRANSB ? 44 : BK;   // 44: 8B-aligned rows, ~8-way wr
  constexpr int BSZ  = GBN * BSTR;
  __shared__ __align__(16) ushort sm[(NPROD == 3) ? (2 * ASZ + 2 * BSZ)
                                                  : (ASZ + BSZ)];
  ushort* sAhi = sm;
  ushort* sBhi = sm + ASZ;
  ushort* sAlo = sm + ASZ + BSZ;       // NPROD==3 only
  ushort* sBlo = sm + 2 * ASZ + BSZ;

  const int tid  = threadIdx.x;
  const int lane = tid & 63;
  const int wid  = tid >> 6;
  const int r    = lane & 15;     // A row / B col / C col
  const int gg   = lane >> 4;     // k-group; C row group
  const int wrow = wid >> 1;
  const int wcol = wid & 1;

  // bijective XCD-aware block swizzle (m204)
  const int gx = gridDim.x, gy = gridDim.y;
  const int nwg = gx * gy;
  const int orig = blockIdx.x + gx * blockIdx.y;
  const int qq = nwg >> 3, rr = nwg & 7;
  const int xcd = orig & 7, idx = orig >> 3;
  const int wg = (xcd < rr ? xcd * (qq + 1) : rr * (qq + 1) + (xcd - rr) * qq) + idx;
  const int nbase = (wg % gx) * GBN;
  const int mbase = (wg / gx) * GBM;
  const int b     = blockIdx.z;

  const ushort* Ahi = g.Ahi + (size_t)b * g.sAb;
  const ushort* Bhi = g.Bhi + (size_t)b * g.sBb;
  const ushort* Alo = (NPROD == 3) ? (g.Alo + (size_t)b * g.sAb) : (const ushort*)nullptr;
  const ushort* Blo = (NPROD == 3) ? (g.Blo + (size_t)b * g.sBb) : (const ushort*)nullptr;

  f32x4 acc[4][4];
#pragma unroll
  for (int i = 0; i < 4; ++i)
#pragma unroll
    for (int j = 0; j < 4; ++j) {
      acc[i][j][0] = 0.f; acc[i][j][1] = 0.f; acc[i][j][2] = 0.f; acc[i][j][3] = 0.f;
    }

  const int wvb = wid << 10;   // wave-uniform LDS byte base within round

  // per-lane source swizzle for staging: dest byte = rd*4096 + tid*16 (linear)
  // row = dest>>KSH2, slot = (dest>>4)&SMASK, src col = (slot^(row&SMASK))*8
  for (int kk = 0; kk < g.K; kk += BK) {
    __syncthreads();
#pragma unroll
    for (int rd = 0; rd < BK / 16; ++rd) {
      const int boff = rd * 4096 + tid * 16;
      const int row  = boff >> KSH2;
      const int slot = (boff >> 4) & SMASK;
      const int scol = ((slot ^ (row & SMASK)) << 3);   // ushort col
      const size_t gaoff = (size_t)(mbase + row) * g.lda + (kk + scol);
      gload16(Ahi + gaoff, (char*)sAhi + rd * 4096 + wvb);
      if (NPROD == 3)
        gload16(Alo + gaoff, (char*)sAlo + rd * 4096 + wvb);
      if (!TRANSB) {
        const size_t gboff = (size_t)(nbase + row) * g.ldb + (kk + scol);
        gload16(Bhi + gboff, (char*)sBhi + rd * 4096 + wvb);
        if (NPROD == 3)
          gload16(Blo + gboff, (char*)sBlo + rd * 4096 + wvb);
      }
    }
    if (TRANSB) {
      // B stored [K][N]: read coalesced along N, transpose into LDS [n][k]
#pragma unroll
      for (int rd = 0; rd < (BK * 128) / 2048; ++rd) {
        const int lin = tid * 8 + rd * 2048;
        const int kr = lin >> 7, nc = lin & 127;
        union { short8v v; ushort u[8]; } t;
        t.v = *(const short8v*)(Bhi + (size_t)(kk + kr) * g.ldb + (nbase + nc));
#pragma unroll
        for (int e = 0; e < 8; ++e)
          sBhi[(nc + e) * BSTR + kr] = t.u[e];
      }
    }
    __syncthreads();

    // ---- fragments + MFMA ----
#pragma unroll
    for (int kb = 0; kb < BK / 32; ++kb) {
      const int cbk = kb * 64 + gg * 8;     // byte offset of k-chunk in row
      short8v aH[4], bH[4], aL[4], bL[4];
#pragma unroll
      for (int i = 0; i < 4; ++i) {
        const int arow = wrow * 64 + i * 16 + r;
        aH[i] = frag_ld<BK>(sAhi, arow, cbk);
        if (NPROD == 3) aL[i] = frag_ld<BK>(sAlo, arow, cbk);
      }
#pragma unroll
      for (int j = 0; j < 4; ++j) {
        const int brow = wcol * 64 + j * 16 + r;
        if (!TRANSB) {
          bH[j] = frag_ld<BK>(sBhi, brow, cbk);
          if (NPROD == 3) bL[j] = frag_ld<BK>(sBlo, brow, cbk);
        } else {
          bH[j] = load_frag(sBhi + brow * BSTR + kb * 32 + gg * 4);
        }
      }
#pragma unroll
      for (int i = 0; i < 4; ++i)
#pragma unroll
        for (int j = 0; j < 4; ++j) {
          acc[i][j] = __builtin_amdgcn_mfma_f32_16x16x32_bf16(aH[i], bH[j], acc[i][j], 0, 0, 0);
          if (NPROD == 3) {
            acc[i][j] = __builtin_amdgcn_mfma_f32_16x16x32_bf16(aH[i], bL[j], acc[i][j], 0, 0, 0);
            acc[i][j] = __builtin_amdgcn_mfma_f32_16x16x32_bf16(aL[i], bH[j], acc[i][j], 0, 0, 0);
          }
        }
    }
  }

  // ---- epilogue.  C/D layout: col = lane&15, row = (lane>>4)*4 + reg ----
#pragma unroll
  for (int i = 0; i < 4; ++i)
#pragma unroll
    for (int j = 0; j < 4; ++j)
#pragma unroll
      for (int e = 0; e < 4; ++e) {
        const int row = mbase + wrow * 64 + i * 16 + gg * 4 + e;
        const int col = nbase + wcol * 64 + j * 16 + r;
        float val = acc[i][j][e];
        if (EPI == EPI_QK) {
          val += g.bias[col];
          ushort hi = f2bf(val);
          ushort lo = f2bf(val - b2f(hi));
          size_t o = (size_t)row * g.ldo + col;
          g.outHi[o] = hi; g.outLo[o] = lo;
        } else if (EPI == EPI_V) {
          val += g.bias[col];
          g.outHi[(size_t)row * g.ldo + col] = f2bf(val);
        } else if (EPI == EPI_SCORE) {
          if (row < g.Mv && col < g.Nv)
            (g.outF + (size_t)b * g.sOb)[(size_t)row * g.ldo + col] = val * g.scale;
        } else if (EPI == EPI_PV) {
          if (row < g.Mv) {
            val += (g.resid + (size_t)b * g.sRb)[(size_t)row * g.ldr + col];
            (g.outF + (size_t)b * g.sOb)[(size_t)row * g.ldo + col] = val;
          }
        } else if (EPI == EPI_GELU) {
          val = gelu_f(val + g.bias[col]);
          g.outHi[(size_t)row * g.ldo + col] = f2bf(val);
        } else { // EPI_OUT
          if (row < g.Mv) {
            val = gelu_f(val + g.bias[col]);
            val += g.resid[(size_t)row * g.ldr + col];
            g.outF[(size_t)row * g.ldo + col] = val;
          }
        }
      }
}

// ---------------------------------------------------------------------------
// Host side
// ---------------------------------------------------------------------------
extern "C" void kernel_launch(void* const* d_in, const int* in_sizes, int n_in,
                              void* d_out, int out_size, void* d_ws, size_t ws_size,
                              hipStream_t stream) {
  const float* x   = (const float*)d_in[0];
  const float* n1w = (const float*)d_in[1];
  const float* n1b = (const float*)d_in[2];
  const float* Wq  = (const float*)d_in[3];
  const float* bq  = (const float*)d_in[4];
  const float* Wk  = (const float*)d_in[5];
  const float* bk  = (const float*)d_in[6];
  const float* Wv  = (const float*)d_in[7];
  const float* bv  = (const float*)d_in[8];
  const float* n2w = (const float*)d_in[9];
  const float* n2b = (const float*)d_in[10];
  const float* W1  = (const float*)d_in[11];
  const float* b1  = (const float*)d_in[12];
  const float* W2  = (const float*)d_in[13];
  const float* b2  = (const float*)d_in[14];
  float* out = (float*)d_out;

  char* ws = (char*)d_ws;
  size_t off = 0;
  auto alloc = [&](size_t bytes) -> char* {
    char* p = ws + off;
    off += (bytes + 255) & ~(size_t)255;
    return p;
  };
  const size_t szDD  = (size_t)DIM * DIM * 2;      // 768x768 bf16
  const size_t szDH  = (size_t)DIM * HDIM * 2;     // 768x3072 bf16
  const size_t szAct = (size_t)NTP * DIM * 2;      // padded activation bf16

  ushort* wqtH = (ushort*)alloc(szDD);
  ushort* wqtL = (ushort*)alloc(szDD);
  ushort* wktH = (ushort*)alloc(szDD);
  ushort* wktL = (ushort*)alloc(szDD);
  ushort* wvtH = (ushort*)alloc(szDD);
  ushort* w1tH = (ushort*)alloc(szDH);
  ushort* w2tH = (ushort*)alloc(szDH);
  ushort* hHi  = (ushort*)alloc(szAct);
  ushort* hLo  = (ushort*)alloc(szAct);
  ushort* qHi  = (ushort*)alloc(szAct);
  ushort* qLo  = (ushort*)alloc(szAct);
  ushort* kHi  = (ushort*)alloc(szAct);
  ushort* kLo  = (ushort*)alloc(szAct);
  ushort* vB   = (ushort*)alloc(szAct);
  float*  scoresWs = (float*)alloc((size_t)BATCH * SROWS * SCOLS * 4);
  ushort* pWs      = (ushort*)alloc((size_t)BATCH * PROWS * SCOLS * 2);
  float*  lnPart   = (float*)alloc((size_t)BATCH * LN_CH * 2 * 4);
  float*  lnStats  = (float*)alloc((size_t)BATCH * 2 * 4);
  if (off > ws_size) return;  // workspace too small -> fail loudly

  // Aliases (lifetimes disjoint):
  float*  x2  = (float*)hHi;   // NTP*768*4 == 2 * szAct (hHi+hLo)
  ushort* h2  = vB;            // after PV, v no longer needed
  ushort* hid = qHi;           // NTP*3072*2 == 4 * szAct (qHi..kLo block)

  const float SCALE_F = 14.035668847618199f;  // sqrt(197) == 1/S**(-0.5)

  dim3 tb(32, 8);
  hipLaunchKernelGGL((transp_k<true >), dim3(DIM / 32, DIM / 32), tb, 0, stream, Wq, DIM, DIM, wqtH, wqtL);
  hipLaunchKernelGGL((transp_k<true >), dim3(DIM / 32, DIM / 32), tb, 0, stream, Wk, DIM, DIM, wktH, wktL);
  hipLaunchKernelGGL((transp_k<false>), dim3(DIM / 32, DIM / 32), tb, 0, stream, Wv, DIM, DIM, wvtH, (ushort*)nullptr);
  hipLaunchKernelGGL((transp_k<false>), dim3(HDIM / 32, DIM / 32), tb, 0, stream, W1, DIM, HDIM, w1tH, (ushort*)nullptr);
  hipLaunchKernelGGL((transp_k<false>), dim3(DIM / 32, HDIM / 32), tb, 0, stream, W2, HDIM, DIM, w2tH, (ushort*)nullptr);

  const int APPLY_BX = (SD / 4 + 255) / 256;
  hipLaunchKernelGGL(ln_part_k, dim3(LN_CH, BATCH), dim3(256), 0, stream, x, lnPart);
  hipLaunchKernelGGL(ln_fin_k, dim3(1), dim3(64), 0, stream, lnPart, lnStats);
  hipLaunchKernelGGL((ln_apply_k<true>), dim3(APPLY_BX, BATCH), dim3(256), 0, stream,
                     x, n1w, n1b, lnStats, hHi, hLo);

  GemmArgs a;
  const int BIG = 0x40000000;

  // Q projection (split, BK=32)
  a = GemmArgs{};
  a.Ahi = hHi; a.Alo = hLo; a.sAb = 0; a.lda = DIM;
  a.Bhi = wqtH; a.Blo = wqtL; a.sBb = 0; a.ldb = DIM;
  a.K = DIM; a.Mv = BIG; a.Nv = BIG; a.bias = bq; a.scale = 1.f;
  a.outHi = qHi; a.outLo = qLo; a.ldo = DIM;
  hipLaunchKernelGGL((gemm_k<3, false, EPI_QK, 32>), dim3(DIM / GBN, NTP / GBM, 1), dim3(256), 0, stream, a);
  // K projection (split)
  a.Bhi = wktH; a.Blo = wktL; a.bias = bk; a.outHi = kHi; a.outLo = kLo;
  hipLaunchKernelGGL((gemm_k<3, false, EPI_QK, 32>), dim3(DIM / GBN, NTP / GBM, 1), dim3(256), 0, stream, a);
  // V projection (single, BK=64)
  a = GemmArgs{};
  a.Ahi = hHi; a.sAb = 0; a.lda = DIM;
  a.Bhi = wvtH; a.sBb = 0; a.ldb = DIM;
  a.K = DIM; a.Mv = BIG; a.Nv = BIG; a.bias = bv;
  a.outHi = vB; a.ldo = DIM;
  hipLaunchKernelGGL((gemm_k<1, false, EPI_V, 64>), dim3(DIM / GBN, NTP / GBM, 1), dim3(256), 0, stream, a);

  // scores = SCALE * q k^T  (batched, split)
  a = GemmArgs{};
  a.Ahi = qHi; a.Alo = qLo; a.sAb = (size_t)SD; a.lda = DIM;
  a.Bhi = kHi; a.Blo = kLo; a.sBb = (size_t)SD; a.ldb = DIM;
  a.K = DIM; a.Mv = S_LEN; a.Nv = S_LEN; a.scale = SCALE_F;
  a.outF = scoresWs; a.sOb = (size_t)SROWS * SCOLS; a.ldo = SCOLS;
  hipLaunchKernelGGL((gemm_k<3, false, EPI_SCORE, 32>), dim3(2, 2, BATCH), dim3(256), 0, stream, a);

  hipLaunchKernelGGL(softmax_k, dim3(S_LEN, BATCH), dim3(64), 0, stream, scoresWs, pWs);

  // x2 = P v + x  (batched; B = v stored [K][N] -> TRANSB staging, BK=32)
  a = GemmArgs{};
  a.Ahi = pWs; a.sAb = (size_t)PROWS * SCOLS; a.lda = SCOLS;
  a.Bhi = vB; a.sBb = (size_t)SD; a.ldb = DIM;
  a.K = SCOLS; a.Mv = S_LEN; a.Nv = BIG;
  a.resid = x; a.sRb = (size_t)SD; a.ldr = DIM;
  a.outF = x2; a.sOb = (size_t)SD; a.ldo = DIM;
  hipLaunchKernelGGL((gemm_k<1, true, EPI_PV, 32>), dim3(DIM / GBN, 2, BATCH), dim3(256), 0, stream, a);

  hipLaunchKernelGGL(ln_part_k, dim3(LN_CH, BATCH), dim3(256), 0, stream, x2, lnPart);
  hipLaunchKernelGGL(ln_fin_k, dim3(1), dim3(64), 0, stream, lnPart, lnStats);
  hipLaunchKernelGGL((ln_apply_k<false>), dim3(APPLY_BX, BATCH), dim3(256), 0, stream,
                     x2, n2w, n2b, lnStats, h2, (ushort*)nullptr);

  // hid = gelu(h2 W1 + b1)
  a = GemmArgs{};
  a.Ahi = h2; a.sAb = 0; a.lda = DIM;
  a.Bhi = w1tH; a.sBb = 0; a.ldb = DIM;
  a.K = DIM; a.Mv = BIG; a.Nv = BIG; a.bias = b1;
  a.outHi = hid; a.ldo = HDIM;
  hipLaunchKernelGGL((gemm_k<1, false, EPI_GELU, 64>), dim3(HDIM / GBN, NTP / GBM, 1), dim3(256), 0, stream, a);

  // out = gelu(hid W2 + b2) + x2
  a = GemmArgs{};
  a.Ahi = hid; a.sAb = 0; a.lda = HDIM;
  a.Bhi = w2tH; a.sBb = 0; a.ldb = HDIM;
  a.K = HDIM; a.Mv = NT; a.Nv = BIG; a.bias = b2;
  a.resid = x2; a.sRb = 0; a.ldr = DIM;
  a.outF = out; a.sOb = 0; a.ldo = DIM;
  hipLaunchKernelGGL((gemm_k<1, false, EPI_OUT, 64>), dim3(DIM / GBN, NTP / GBM, 1), dim3(256), 0, stream, a);
}

// Round 6
// 753.311 us; speedup vs baseline: 2.3126x; 1.2441x over previous
//
#include <hip/hip_runtime.h>
#include <math.h>

// ---------------------------------------------------------------------------
// TransformerEncoder on MI355X (gfx950).
// bf16 MFMA everywhere; h -> q,k -> scores path uses hi/lo bf16-split GEMMs
// (3 MFMA products) because SCALE=sqrt(197) makes softmax near-argmax.
// Round 5 (resubmission — GPUAcquisitionTimeout, no data): T3 "minimum
// 2-phase" — double-buffered LDS, stage(t+1) issued BEFORE compute(t), ONE
// barrier per K-step (compiler's pre-barrier vmcnt(0) drain is then nearly
// free). Plus tanh-form GELU (erff epilogue was costing more VALU than the
// MFMA at K=768).
// ---------------------------------------------------------------------------

#define S_LEN 197
#define DIM   768
#define HDIM  3072
#define BATCH 64
#define NT    (BATCH * S_LEN)   // 12608 tokens
#define NTP   12672             // NT padded to multiple of 128
#define SD    (S_LEN * DIM)     // 151296 elements per batch sample
#define SROWS 208               // scores ws rows per batch (alloc)
#define SCOLS 224               // scores/P cols per batch (K-pad for PV)
#define PROWS 256               // P ws rows per batch (alloc, 2x128 tiles)

typedef __attribute__((ext_vector_type(4))) float  f32x4;
typedef __attribute__((ext_vector_type(8))) short  short8v;
typedef __attribute__((ext_vector_type(4))) short  short4v;
typedef __attribute__((ext_vector_type(4))) unsigned short ushort4v;

__device__ __forceinline__ ushort f2bf(float f) {   // RNE float->bf16 bits
  union { float f; unsigned u; } a; a.f = f;
  unsigned u = a.u;
  u += 0x7FFFu + ((u >> 16) & 1u);
  return (ushort)(u >> 16);
}
__device__ __forceinline__ float b2f(ushort h) {
  union { unsigned u; float f; } a; a.u = ((unsigned)h) << 16;
  return a.f;
}
// tanh-form gelu (max abs err ~1e-3 vs exact; ~8 VALU ops vs ~25 for erff)
__device__ __forceinline__ float gelu_f(float x) {
  float x3 = x * x * x;
  float y2 = 1.5957691216057308f * (x + 0.044715f * x3);  // 2*c1*(x+c2 x^3)
  float e  = __expf(y2);
  float t  = 1.0f - 2.0f / (e + 1.0f);                     // tanh(y)
  return 0.5f * x * (1.0f + t);
}
__device__ __forceinline__ void gload16(const void* g, void* l) {
  __builtin_amdgcn_global_load_lds(
      (const __attribute__((address_space(1))) void*)g,
      (__attribute__((address_space(3))) void*)l, 16, 0, 0);
}

// ---------------------------------------------------------------------------
// Weight transpose + bf16 (hi[/lo]) split:  W[K][N] -> T[N][K]
// ---------------------------------------------------------------------------
template<bool SPLIT>
__global__ __launch_bounds__(256) void transp_k(const float* __restrict__ W,
                                                int K, int N,
                                                ushort* __restrict__ Thi,
                                                ushort* __restrict__ Tlo) {
  __shared__ float tile[32][33];
  const int nb = blockIdx.x * 32, kb = blockIdx.y * 32;
  const int tx = threadIdx.x, ty = threadIdx.y;   // (32, 8)
#pragma unroll
  for (int i = 0; i < 4; ++i)
    tile[ty + i * 8][tx] = W[(size_t)(kb + ty + i * 8) * N + nb + tx];
  __syncthreads();
#pragma unroll
  for (int i = 0; i < 4; ++i) {
    float v = tile[tx][ty + i * 8];             // = W[kb+tx][nb+ty+i*8]
    size_t o = (size_t)(nb + ty + i * 8) * K + kb + tx;
    ushort h = f2bf(v);
    Thi[o] = h;
    if (SPLIT) Tlo[o] = f2bf(v - b2f(h));
  }
}

// ---------------------------------------------------------------------------
// LayerNorm, split into partial-reduce / finalize / apply for full-GPU BW
// ---------------------------------------------------------------------------
#define LN_CH 4
__global__ __launch_bounds__(256) void ln_part_k(const float* __restrict__ x,
                                                 float* __restrict__ pbuf) {
  const int c = blockIdx.x, b = blockIdx.y;
  const float4* xv = (const float4*)(x + (size_t)b * SD);
  const int per = (SD / 4) / LN_CH;   // 9456
  float sum = 0.f, sq = 0.f;
  for (int i = c * per + threadIdx.x; i < (c + 1) * per; i += 256) {
    float4 v = xv[i];
    sum += (v.x + v.y) + (v.z + v.w);
    sq  += (v.x * v.x + v.y * v.y) + (v.z * v.z + v.w * v.w);
  }
#pragma unroll
  for (int o = 32; o > 0; o >>= 1) {
    sum += __shfl_xor(sum, o); sq += __shfl_xor(sq, o);
  }
  __shared__ float s1[4], s2[4];
  if ((threadIdx.x & 63) == 0) { s1[threadIdx.x >> 6] = sum; s2[threadIdx.x >> 6] = sq; }
  __syncthreads();
  if (threadIdx.x == 0) {
    pbuf[(b * LN_CH + c) * 2]     = s1[0] + s1[1] + s1[2] + s1[3];
    pbuf[(b * LN_CH + c) * 2 + 1] = s2[0] + s2[1] + s2[2] + s2[3];
  }
}

__global__ __launch_bounds__(64) void ln_fin_k(const float* __restrict__ pbuf,
                                               float* __restrict__ stats) {
  const int b = threadIdx.x;
  float S = 0.f, Q = 0.f;
#pragma unroll
  for (int c = 0; c < LN_CH; ++c) {
    S += pbuf[(b * LN_CH + c) * 2];
    Q += pbuf[(b * LN_CH + c) * 2 + 1];
  }
  const float mu = S / (float)SD;
  const float var = Q / (float)SD - mu * mu;
  stats[b * 2] = mu;
  stats[b * 2 + 1] = 1.0f / sqrtf(var + 1e-5f);
}

template<bool SPLIT>
__global__ __launch_bounds__(256) void ln_apply_k(const float* __restrict__ x,
                                                  const float* __restrict__ w,
                                                  const float* __restrict__ bb,
                                                  const float* __restrict__ stats,
                                                  ushort* __restrict__ oHi,
                                                  ushort* __restrict__ oLo) {
  const int b = blockIdx.y;
  const int i = blockIdx.x * 256 + threadIdx.x;
  if (i >= SD / 4) return;
  const float mu = stats[b * 2], rs = stats[b * 2 + 1];
  float4 v  = ((const float4*)(x + (size_t)b * SD))[i];
  float4 W4 = ((const float4*)w)[i];
  float4 B4 = ((const float4*)bb)[i];
  float h0 = (v.x - mu) * rs * W4.x + B4.x;
  float h1 = (v.y - mu) * rs * W4.y + B4.y;
  float h2 = (v.z - mu) * rs * W4.z + B4.z;
  float h3 = (v.w - mu) * rs * W4.w + B4.w;
  ushort4v hh;
  hh[0] = f2bf(h0); hh[1] = f2bf(h1); hh[2] = f2bf(h2); hh[3] = f2bf(h3);
  ((ushort4v*)(oHi + (size_t)b * SD))[i] = hh;
  if (SPLIT) {
    ushort4v ll;
    ll[0] = f2bf(h0 - b2f(hh[0]));
    ll[1] = f2bf(h1 - b2f(hh[1]));
    ll[2] = f2bf(h2 - b2f(hh[2]));
    ll[3] = f2bf(h3 - b2f(hh[3]));
    ((ushort4v*)(oLo + (size_t)b * SD))[i] = ll;
  }
}

// ---------------------------------------------------------------------------
// Row softmax over 197 valid cols; writes P (bf16) with cols [197,224) zeroed
// ---------------------------------------------------------------------------
__global__ __launch_bounds__(64) void softmax_k(const float* __restrict__ scores,
                                                ushort* __restrict__ P) {
  const int s = blockIdx.x, b = blockIdx.y;
  const int lane = threadIdx.x;
  const float* row = scores + ((size_t)b * SROWS + s) * SCOLS;
  float v[4];
  float m = -1e30f;
#pragma unroll
  for (int t = 0; t < 4; ++t) {
    int c = lane + t * 64;
    v[t] = (c < S_LEN) ? row[c] : -1e30f;
    m = fmaxf(m, v[t]);
  }
#pragma unroll
  for (int off = 32; off > 0; off >>= 1) m = fmaxf(m, __shfl_xor(m, off));
  float sum = 0.f;
#pragma unroll
  for (int t = 0; t < 4; ++t) {
    int c = lane + t * 64;
    v[t] = (c < S_LEN) ? expf(v[t] - m) : 0.f;
    sum += v[t];
  }
#pragma unroll
  for (int off = 32; off > 0; off >>= 1) sum += __shfl_xor(sum, off);
  const float inv = 1.0f / sum;
  ushort* prow = P + ((size_t)b * PROWS + s) * SCOLS;
#pragma unroll
  for (int t = 0; t < 4; ++t) {
    int c = lane + t * 64;
    if (c < SCOLS) prow[c] = f2bf(v[t] * inv);
  }
}

// ---------------------------------------------------------------------------
// MFMA GEMM: C[M][N] = A[M][K] * B^T (B stored [N][K] unless TRANSB:
// B stored [K][N], transposed during LDS staging; single-buffered path).
// NPROD==3: hi/lo split (Ahi*Bhi + Ahi*Blo + Alo*Bhi).
// Tile 128x128xBK, 256 threads (4 waves 2x2), mfma_f32_16x16x32_bf16,
// global_load_lds width=16 into linear LDS with 16B-slot XOR swizzle:
//   physical_slot = logical_slot ^ (row & SMASK)    (involution)
// Non-TRANSB path is 2-phase double-buffered: STAGE(t+1) issued before
// COMPUTE(t); single __syncthreads per step (its implicit vmcnt(0) drain
// lands after the whole compute phase -> loads already returned).
// ---------------------------------------------------------------------------
#define GBM 128
#define GBN 128

enum { EPI_QK = 0, EPI_V, EPI_SCORE, EPI_PV, EPI_GELU, EPI_OUT };

struct GemmArgs {
  const ushort* Ahi; const ushort* Alo; size_t sAb; int lda;
  const ushort* Bhi; const ushort* Blo; size_t sBb; int ldb;
  int K; int Mv; int Nv;
  const float* bias;
  const float* resid; size_t sRb; int ldr;
  float scale;
  float* outF; size_t sOb; int ldo;
  ushort* outHi; ushort* outLo;
};

// swizzled fragment load from a linear [128][BK] bf16 tile.
// cb = byte offset of k-chunk within row (kb*64 + gg*8); reads cb and cb+32.
template<int BK>
__device__ __forceinline__ short8v frag_ld(const ushort* tile, int row, int cb) {
  constexpr int SMASK = (BK * 2) / 16 - 1;      // 7 (BK=64) or 3 (BK=32)
  const char* base = (const char*)tile + row * (BK * 2);
  const int xr = (row & SMASK) << 4;
  const int c1 = cb + 32;
  union U { short8v v8; struct P4 { short4v a, b; } p4; } f;
  f.p4.a = *(const short4v*)(base + ((( cb & ~15) ^ xr) | (cb & 15)));
  f.p4.b = *(const short4v*)(base + (((c1 & ~15) ^ xr) | (c1 & 15)));
  return f.v8;
}

// plain (padded-stride) fragment load — TRANSB register-staged B tile
__device__ __forceinline__ short8v load_frag(const ushort* p) {
  union U { short8v v8; struct P4 { short4v a, b; } p4; } f;
  f.p4.a = *(const short4v*)(p);        // k = 4*g + [0..3]
  f.p4.b = *(const short4v*)(p + 16);   // k = 16 + 4*g + [0..3]
  return f.v8;
}

template<int NPROD, bool TRANSB, int EPI, int BK>
__global__ __launch_bounds__(256) void gemm_k(GemmArgs g) {
  constexpr int KSH2 = (BK == 64) ? 7 : 6;   // log2(bytes per row)
  constexpr int SMASK = (BK * 2) / 16 - 1;
  constexpr int ASZ  = GBM * BK;
  constexpr int BSTR = TRANSB ? 44 : BK;   // 44: 8B-aligned rows, ~8-way wr
  constexpr int BSZ  = GBN * BSTR;
  constexpr int BUFSZ = (NPROD == 3) ? (2 * ASZ + 2 * BSZ) : (ASZ + BSZ);
  __shared__ __align__(16) ushort sm[TRANSB ? (ASZ + BSZ) : 2 * BUFSZ];

  const int tid  = threadIdx.x;
  const int lane = tid & 63;
  const int wid  = tid >> 6;
  const int r    = lane & 15;     // A row / B col / C col
  const int gg   = lane >> 4;     // k-group; C row group
  const int wrow = wid >> 1;
  const int wcol = wid & 1;

  // bijective XCD-aware block swizzle (m204)
  const int gx = gridDim.x, gy = gridDim.y;
  const int nwg = gx * gy;
  const int orig = blockIdx.x + gx * blockIdx.y;
  const int qq = nwg >> 3, rr = nwg & 7;
  const int xcd = orig & 7, idx = orig >> 3;
  const int wg = (xcd < rr ? xcd * (qq + 1) : rr * (qq + 1) + (xcd - rr) * qq) + idx;
  const int nbase = (wg % gx) * GBN;
  const int mbase = (wg / gx) * GBM;
  const int b     = blockIdx.z;

  const ushort* Ahi = g.Ahi + (size_t)b * g.sAb;
  const ushort* Bhi = g.Bhi + (size_t)b * g.sBb;
  const ushort* Alo = (NPROD == 3) ? (g.Alo + (size_t)b * g.sAb) : (const ushort*)nullptr;
  const ushort* Blo = (NPROD == 3) ? (g.Blo + (size_t)b * g.sBb) : (const ushort*)nullptr;

  f32x4 acc[4][4];
#pragma unroll
  for (int i = 0; i < 4; ++i)
#pragma unroll
    for (int j = 0; j < 4; ++j) {
      acc[i][j][0] = 0.f; acc[i][j][1] = 0.f; acc[i][j][2] = 0.f; acc[i][j][3] = 0.f;
    }

  const int wvb = wid << 10;   // wave-uniform LDS byte base within round

  // stage one K-tile into buffer at `base` (pre-swizzled global source)
  auto STAGE = [&](int kk, ushort* base) {
    ushort* dA  = base;
    ushort* dB  = base + ASZ;
    ushort* dAl = base + ASZ + BSZ;
    ushort* dBl = base + 2 * ASZ + BSZ;
#pragma unroll
    for (int rd = 0; rd < BK / 16; ++rd) {
      const int boff = rd * 4096 + tid * 16;
      const int row  = boff >> KSH2;
      const int slot = (boff >> 4) & SMASK;
      const int scol = ((slot ^ (row & SMASK)) << 3);   // ushort col
      const size_t gaoff = (size_t)(mbase + row) * g.lda + (kk + scol);
      gload16(Ahi + gaoff, (char*)dA + rd * 4096 + wvb);
      if (NPROD == 3)
        gload16(Alo + gaoff, (char*)dAl + rd * 4096 + wvb);
      const size_t gboff = (size_t)(nbase + row) * g.ldb + (kk + scol);
      gload16(Bhi + gboff, (char*)dB + rd * 4096 + wvb);
      if (NPROD == 3)
        gload16(Blo + gboff, (char*)dBl + rd * 4096 + wvb);
    }
  };

  auto COMPUTE = [&](const ushort* base) {
    const ushort* cA  = base;
    const ushort* cB  = base + ASZ;
    const ushort* cAl = base + ASZ + BSZ;
    const ushort* cBl = base + 2 * ASZ + BSZ;
#pragma unroll
    for (int kb = 0; kb < BK / 32; ++kb) {
      const int cbk = kb * 64 + gg * 8;     // byte offset of k-chunk in row
      short8v aH[4], bH[4], aL[4], bL[4];
#pragma unroll
      for (int i = 0; i < 4; ++i) {
        const int arow = wrow * 64 + i * 16 + r;
        aH[i] = frag_ld<BK>(cA, arow, cbk);
        if (NPROD == 3) aL[i] = frag_ld<BK>(cAl, arow, cbk);
      }
#pragma unroll
      for (int j = 0; j < 4; ++j) {
        const int brow = wcol * 64 + j * 16 + r;
        bH[j] = frag_ld<BK>(cB, brow, cbk);
        if (NPROD == 3) bL[j] = frag_ld<BK>(cBl, brow, cbk);
      }
#pragma unroll
      for (int i = 0; i < 4; ++i)
#pragma unroll
        for (int j = 0; j < 4; ++j) {
          acc[i][j] = __builtin_amdgcn_mfma_f32_16x16x32_bf16(aH[i], bH[j], acc[i][j], 0, 0, 0);
          if (NPROD == 3) {
            acc[i][j] = __builtin_amdgcn_mfma_f32_16x16x32_bf16(aH[i], bL[j], acc[i][j], 0, 0, 0);
            acc[i][j] = __builtin_amdgcn_mfma_f32_16x16x32_bf16(aL[i], bH[j], acc[i][j], 0, 0, 0);
          }
        }
    }
  };

  if (!TRANSB) {
    // ---- 2-phase double-buffered main loop ----
    STAGE(0, sm);
    __syncthreads();
    const int nst = g.K / BK;
    for (int t = 0; t < nst; ++t) {
      ushort* cur = sm + (t & 1) * BUFSZ;
      ushort* nxt = sm + ((t & 1) ^ 1) * BUFSZ;
      if (t + 1 < nst) STAGE((t + 1) * BK, nxt);
      COMPUTE(cur);
      if (t + 1 < nst) __syncthreads();
    }
  } else {
    // ---- single-buffered path with register-transposed B ----
    ushort* sAhi = sm;
    ushort* sBhi = sm + ASZ;
    for (int kk = 0; kk < g.K; kk += BK) {
      __syncthreads();
#pragma unroll
      for (int rd = 0; rd < BK / 16; ++rd) {
        const int boff = rd * 4096 + tid * 16;
        const int row  = boff >> KSH2;
        const int slot = (boff >> 4) & SMASK;
        const int scol = ((slot ^ (row & SMASK)) << 3);
        const size_t gaoff = (size_t)(mbase + row) * g.lda + (kk + scol);
        gload16(Ahi + gaoff, (char*)sAhi + rd * 4096 + wvb);
      }
#pragma unroll
      for (int rd = 0; rd < (BK * 128) / 2048; ++rd) {
        const int lin = tid * 8 + rd * 2048;
        const int kr = lin >> 7, nc = lin & 127;
        union { short8v v; ushort u[8]; } t;
        t.v = *(const short8v*)(Bhi + (size_t)(kk + kr) * g.ldb + (nbase + nc));
#pragma unroll
        for (int e = 0; e < 8; ++e)
          sBhi[(nc + e) * BSTR + kr] = t.u[e];
      }
      __syncthreads();
#pragma unroll
      for (int kb = 0; kb < BK / 32; ++kb) {
        const int cbk = kb * 64 + gg * 8;
        short8v aH[4], bH[4];
#pragma unroll
        for (int i = 0; i < 4; ++i)
          aH[i] = frag_ld<BK>(sAhi, wrow * 64 + i * 16 + r, cbk);
#pragma unroll
        for (int j = 0; j < 4; ++j)
          bH[j] = load_frag(sBhi + (wcol * 64 + j * 16 + r) * BSTR + kb * 32 + gg * 4);
#pragma unroll
        for (int i = 0; i < 4; ++i)
#pragma unroll
          for (int j = 0; j < 4; ++j)
            acc[i][j] = __builtin_amdgcn_mfma_f32_16x16x32_bf16(aH[i], bH[j], acc[i][j], 0, 0, 0);
      }
    }
  }

  // ---- epilogue.  C/D layout: col = lane&15, row = (lane>>4)*4 + reg ----
#pragma unroll
  for (int i = 0; i < 4; ++i)
#pragma unroll
    for (int j = 0; j < 4; ++j)
#pragma unroll
      for (int e = 0; e < 4; ++e) {
        const int row = mbase + wrow * 64 + i * 16 + gg * 4 + e;
        const int col = nbase + wcol * 64 + j * 16 + r;
        float val = acc[i][j][e];
        if (EPI == EPI_QK) {
          val += g.bias[col];
          ushort hi = f2bf(val);
          ushort lo = f2bf(val - b2f(hi));
          size_t o = (size_t)row * g.ldo + col;
          g.outHi[o] = hi; g.outLo[o] = lo;
        } else if (EPI == EPI_V) {
          val += g.bias[col];
          g.outHi[(size_t)row * g.ldo + col] = f2bf(val);
        } else if (EPI == EPI_SCORE) {
          if (row < g.Mv && col < g.Nv)
            (g.outF + (size_t)b * g.sOb)[(size_t)row * g.ldo + col] = val * g.scale;
        } else if (EPI == EPI_PV) {
          if (row < g.Mv) {
            val += (g.resid + (size_t)b * g.sRb)[(size_t)row * g.ldr + col];
            (g.outF + (size_t)b * g.sOb)[(size_t)row * g.ldo + col] = val;
          }
        } else if (EPI == EPI_GELU) {
          val = gelu_f(val + g.bias[col]);
          g.outHi[(size_t)row * g.ldo + col] = f2bf(val);
        } else { // EPI_OUT
          if (row < g.Mv) {
            val = gelu_f(val + g.bias[col]);
            val += g.resid[(size_t)row * g.ldr + col];
            g.outF[(size_t)row * g.ldo + col] = val;
          }
        }
      }
}

// ---------------------------------------------------------------------------
// Host side
// ---------------------------------------------------------------------------
extern "C" void kernel_launch(void* const* d_in, const int* in_sizes, int n_in,
                              void* d_out, int out_size, void* d_ws, size_t ws_size,
                              hipStream_t stream) {
  const float* x   = (const float*)d_in[0];
  const float* n1w = (const float*)d_in[1];
  const float* n1b = (const float*)d_in[2];
  const float* Wq  = (const float*)d_in[3];
  const float* bq  = (const float*)d_in[4];
  const float* Wk  = (const float*)d_in[5];
  const float* bk  = (const float*)d_in[6];
  const float* Wv  = (const float*)d_in[7];
  const float* bv  = (const float*)d_in[8];
  const float* n2w = (const float*)d_in[9];
  const float* n2b = (const float*)d_in[10];
  const float* W1  = (const float*)d_in[11];
  const float* b1  = (const float*)d_in[12];
  const float* W2  = (const float*)d_in[13];
  const float* b2  = (const float*)d_in[14];
  float* out = (float*)d_out;

  char* ws = (char*)d_ws;
  size_t off = 0;
  auto alloc = [&](size_t bytes) -> char* {
    char* p = ws + off;
    off += (bytes + 255) & ~(size_t)255;
    return p;
  };
  const size_t szDD  = (size_t)DIM * DIM * 2;      // 768x768 bf16
  const size_t szDH  = (size_t)DIM * HDIM * 2;     // 768x3072 bf16
  const size_t szAct = (size_t)NTP * DIM * 2;      // padded activation bf16

  ushort* wqtH = (ushort*)alloc(szDD);
  ushort* wqtL = (ushort*)alloc(szDD);
  ushort* wktH = (ushort*)alloc(szDD);
  ushort* wktL = (ushort*)alloc(szDD);
  ushort* wvtH = (ushort*)alloc(szDD);
  ushort* w1tH = (ushort*)alloc(szDH);
  ushort* w2tH = (ushort*)alloc(szDH);
  ushort* hHi  = (ushort*)alloc(szAct);
  ushort* hLo  = (ushort*)alloc(szAct);
  ushort* qHi  = (ushort*)alloc(szAct);
  ushort* qLo  = (ushort*)alloc(szAct);
  ushort* kHi  = (ushort*)alloc(szAct);
  ushort* kLo  = (ushort*)alloc(szAct);
  ushort* vB   = (ushort*)alloc(szAct);
  float*  scoresWs = (float*)alloc((size_t)BATCH * SROWS * SCOLS * 4);
  ushort* pWs      = (ushort*)alloc((size_t)BATCH * PROWS * SCOLS * 2);
  float*  lnPart   = (float*)alloc((size_t)BATCH * LN_CH * 2 * 4);
  float*  lnStats  = (float*)alloc((size_t)BATCH * 2 * 4);
  if (off > ws_size) return;  // workspace too small -> fail loudly

  // Aliases (lifetimes disjoint):
  float*  x2  = (float*)hHi;   // NTP*768*4 == 2 * szAct (hHi+hLo)
  ushort* h2  = vB;            // after PV, v no longer needed
  ushort* hid = qHi;           // NTP*3072*2 == 4 * szAct (qHi..kLo block)

  const float SCALE_F = 14.035668847618199f;  // sqrt(197) == 1/S**(-0.5)

  dim3 tb(32, 8);
  hipLaunchKernelGGL((transp_k<true >), dim3(DIM / 32, DIM / 32), tb, 0, stream, Wq, DIM, DIM, wqtH, wqtL);
  hipLaunchKernelGGL((transp_k<true >), dim3(DIM / 32, DIM / 32), tb, 0, stream, Wk, DIM, DIM, wktH, wktL);
  hipLaunchKernelGGL((transp_k<false>), dim3(DIM / 32, DIM / 32), tb, 0, stream, Wv, DIM, DIM, wvtH, (ushort*)nullptr);
  hipLaunchKernelGGL((transp_k<false>), dim3(HDIM / 32, DIM / 32), tb, 0, stream, W1, DIM, HDIM, w1tH, (ushort*)nullptr);
  hipLaunchKernelGGL((transp_k<false>), dim3(DIM / 32, HDIM / 32), tb, 0, stream, W2, HDIM, DIM, w2tH, (ushort*)nullptr);

  const int APPLY_BX = (SD / 4 + 255) / 256;
  hipLaunchKernelGGL(ln_part_k, dim3(LN_CH, BATCH), dim3(256), 0, stream, x, lnPart);
  hipLaunchKernelGGL(ln_fin_k, dim3(1), dim3(64), 0, stream, lnPart, lnStats);
  hipLaunchKernelGGL((ln_apply_k<true>), dim3(APPLY_BX, BATCH), dim3(256), 0, stream,
                     x, n1w, n1b, lnStats, hHi, hLo);

  GemmArgs a;
  const int BIG = 0x40000000;

  // Q projection (split, BK=32)
  a = GemmArgs{};
  a.Ahi = hHi; a.Alo = hLo; a.sAb = 0; a.lda = DIM;
  a.Bhi = wqtH; a.Blo = wqtL; a.sBb = 0; a.ldb = DIM;
  a.K = DIM; a.Mv = BIG; a.Nv = BIG; a.bias = bq; a.scale = 1.f;
  a.outHi = qHi; a.outLo = qLo; a.ldo = DIM;
  hipLaunchKernelGGL((gemm_k<3, false, EPI_QK, 32>), dim3(DIM / GBN, NTP / GBM, 1), dim3(256), 0, stream, a);
  // K projection (split)
  a.Bhi = wktH; a.Blo = wktL; a.bias = bk; a.outHi = kHi; a.outLo = kLo;
  hipLaunchKernelGGL((gemm_k<3, false, EPI_QK, 32>), dim3(DIM / GBN, NTP / GBM, 1), dim3(256), 0, stream, a);
  // V projection (single, BK=64)
  a = GemmArgs{};
  a.Ahi = hHi; a.sAb = 0; a.lda = DIM;
  a.Bhi = wvtH; a.sBb = 0; a.ldb = DIM;
  a.K = DIM; a.Mv = BIG; a.Nv = BIG; a.bias = bv;
  a.outHi = vB; a.ldo = DIM;
  hipLaunchKernelGGL((gemm_k<1, false, EPI_V, 64>), dim3(DIM / GBN, NTP / GBM, 1), dim3(256), 0, stream, a);

  // scores = SCALE * q k^T  (batched, split)
  a = GemmArgs{};
  a.Ahi = qHi; a.Alo = qLo; a.sAb = (size_t)SD; a.lda = DIM;
  a.Bhi = kHi; a.Blo = kLo; a.sBb = (size_t)SD; a.ldb = DIM;
  a.K = DIM; a.Mv = S_LEN; a.Nv = S_LEN; a.scale = SCALE_F;
  a.outF = scoresWs; a.sOb = (size_t)SROWS * SCOLS; a.ldo = SCOLS;
  hipLaunchKernelGGL((gemm_k<3, false, EPI_SCORE, 32>), dim3(2, 2, BATCH), dim3(256), 0, stream, a);

  hipLaunchKernelGGL(softmax_k, dim3(S_LEN, BATCH), dim3(64), 0, stream, scoresWs, pWs);

  // x2 = P v + x  (batched; B = v stored [K][N] -> TRANSB staging, BK=32)
  a = GemmArgs{};
  a.Ahi = pWs; a.sAb = (size_t)PROWS * SCOLS; a.lda = SCOLS;
  a.Bhi = vB; a.sBb = (size_t)SD; a.ldb = DIM;
  a.K = SCOLS; a.Mv = S_LEN; a.Nv = BIG;
  a.resid = x; a.sRb = (size_t)SD; a.ldr = DIM;
  a.outF = x2; a.sOb = (size_t)SD; a.ldo = DIM;
  hipLaunchKernelGGL((gemm_k<1, true, EPI_PV, 32>), dim3(DIM / GBN, 2, BATCH), dim3(256), 0, stream, a);

  hipLaunchKernelGGL(ln_part_k, dim3(LN_CH, BATCH), dim3(256), 0, stream, x2, lnPart);
  hipLaunchKernelGGL(ln_fin_k, dim3(1), dim3(64), 0, stream, lnPart, lnStats);
  hipLaunchKernelGGL((ln_apply_k<false>), dim3(APPLY_BX, BATCH), dim3(256), 0, stream,
                     x2, n2w, n2b, lnStats, h2, (ushort*)nullptr);

  // hid = gelu(h2 W1 + b1)
  a = GemmArgs{};
  a.Ahi = h2; a.sAb = 0; a.lda = DIM;
  a.Bhi = w1tH; a.sBb = 0; a.ldb = DIM;
  a.K = DIM; a.Mv = BIG; a.Nv = BIG; a.bias = b1;
  a.outHi = hid; a.ldo = HDIM;
  hipLaunchKernelGGL((gemm_k<1, false, EPI_GELU, 64>), dim3(HDIM / GBN, NTP / GBM, 1), dim3(256), 0, stream, a);

  // out = gelu(hid W2 + b2) + x2
  a = GemmArgs{};
  a.Ahi = hid; a.sAb = 0; a.lda = HDIM;
  a.Bhi = w2tH; a.sBb = 0; a.ldb = HDIM;
  a.K = HDIM; a.Mv = NT; a.Nv = BIG; a.bias = b2;
  a.resid = x2; a.sRb = 0; a.ldr = DIM;
  a.outF = out; a.sOb = 0; a.ldo = DIM;
  hipLaunchKernelGGL((gemm_k<1, false, EPI_OUT, 64>), dim3(DIM / GBN, NTP / GBM, 1), dim3(256), 0, stream, a);
}